// Round 14
// baseline (235.584 us; speedup 1.0000x reference)
//
#include <hip/hip_runtime.h>
#include <math.h>

#define IN_F    1024
#define NB      256
#define NL      17
#define BATCH_N 16384
#define RPB     4              // rows per 256-thread block (v4-over-rows regs)
#define NTRP    (NL * 4)       // trace partial slots (17 blocks x 4 waves)

typedef float v4f __attribute__((ext_vector_type(4)));

// bijective involution: spreads the 64B-stride staging writes across bank
// groups (2-way residual = free); applied identically on write and read.
__device__ __forceinline__ int swz(int u) { return u ^ ((u >> 3) & 7); }

// ---------------------------------------------------------------------------
// Kernel 1: expm of 4352 4x4 matrices (f32 scaling-and-squaring + Taylor-9).
// Per-wave trace partials to fixed slots (no atomic, no memset needed).
// (Measured: NOT the bottleneck — f64->f32 didn't move the inter-kernel gap.)
// ---------------------------------------------------------------------------
__global__ __launch_bounds__(256) void expm_kernel(const float* __restrict__ vs,
                                                   float* __restrict__ E,
                                                   float* __restrict__ tr_part) {
    const int m = blockIdx.x * 256 + threadIdx.x;   // 0..4351 (grid exact)
    const float* v = vs + (size_t)m * 16;
    float A[16], X[16], P[16], T[16];
    #pragma unroll
    for (int i = 0; i < 16; ++i) A[i] = v[i];
    const float tr = A[0] + A[5] + A[10] + A[15];

    float n1 = 0.0f;
    #pragma unroll
    for (int j = 0; j < 4; ++j) {
        float c = fabsf(A[j]) + fabsf(A[4 + j]) + fabsf(A[8 + j]) + fabsf(A[12 + j]);
        n1 = fmaxf(n1, c);
    }
    int s = 0;
    while (n1 > 0.25f && s < 30) { n1 *= 0.5f; ++s; }
    const float sc = __int_as_float((127 - s) << 23);   // 2^-s
    #pragma unroll
    for (int i = 0; i < 16; ++i) { A[i] *= sc; P[i] = A[i]; X[i] = A[i]; }
    X[0] += 1.0f; X[5] += 1.0f; X[10] += 1.0f; X[15] += 1.0f;

    #pragma unroll 1
    for (int k = 2; k <= 9; ++k) {
        const float invk = 1.0f / (float)k;
        #pragma unroll
        for (int i = 0; i < 4; ++i)
            #pragma unroll
            for (int j = 0; j < 4; ++j)
                T[i * 4 + j] = P[i * 4 + 0] * A[0 + j] + P[i * 4 + 1] * A[4 + j] +
                               P[i * 4 + 2] * A[8 + j] + P[i * 4 + 3] * A[12 + j];
        #pragma unroll
        for (int i = 0; i < 16; ++i) { P[i] = T[i] * invk; X[i] += P[i]; }
    }
    #pragma unroll 1
    for (int q = 0; q < s; ++q) {
        #pragma unroll
        for (int i = 0; i < 4; ++i)
            #pragma unroll
            for (int j = 0; j < 4; ++j)
                T[i * 4 + j] = X[i * 4 + 0] * X[0 + j] + X[i * 4 + 1] * X[4 + j] +
                               X[i * 4 + 2] * X[8 + j] + X[i * 4 + 3] * X[12 + j];
        #pragma unroll
        for (int i = 0; i < 16; ++i) X[i] = T[i];
    }
    float* e = E + (size_t)m * 16;
    #pragma unroll
    for (int i = 0; i < 16; ++i) e[i] = X[i];

    float tf = tr;
    #pragma unroll
    for (int off = 32; off > 0; off >>= 1) tf += __shfl_down(tf, off);
    if ((threadIdx.x & 63) == 0)
        tr_part[blockIdx.x * 4 + (threadIdx.x >> 6)] = tf;
}

// ---------------------------------------------------------------------------
// Kernel 2: fused flow, feature-major staging.
// LDS unit f = 16B = feature f for all 4 rows. Permutation gather = ONE
// aligned ds_read_b128 per output feature (was 4 random b32). Staging write =
// 4 b128 with XOR swizzle (2-way conflicts = free). Double-buffered 2x16KB ->
// ONE __syncthreads per layer. Registers: z as v4-over-rows per feature.
// ---------------------------------------------------------------------------
__global__ __launch_bounds__(256, 4) void flow_kernel(const float* __restrict__ data,
                                                      const float* __restrict__ E,
                                                      const float* __restrict__ bs,
                                                      const int* __restrict__ idxs,
                                                      const float* __restrict__ tr_part,
                                                      float* __restrict__ out) {
    __shared__ v4f bufA[IN_F];          // 16 KB
    __shared__ v4f bufB[IN_F];          // 16 KB
    __shared__ float red[RPB][4];
    const int t = threadIdx.x;
    const int row0 = blockIdx.x * RPB;

    // load 4 rows (coalesced b128), transpose to feature-major v4-over-rows
    v4f R0 = *(const v4f*)(data + (size_t)(row0 + 0) * IN_F + 4 * t);
    v4f R1 = *(const v4f*)(data + (size_t)(row0 + 1) * IN_F + 4 * t);
    v4f R2 = *(const v4f*)(data + (size_t)(row0 + 2) * IN_F + 4 * t);
    v4f R3 = *(const v4f*)(data + (size_t)(row0 + 3) * IN_F + 4 * t);
    v4f F0 = { R0.x, R1.x, R2.x, R3.x };
    v4f F1 = { R0.y, R1.y, R2.y, R3.y };
    v4f F2 = { R0.z, R1.z, R2.z, R3.z };
    v4f F3 = { R0.w, R1.w, R2.w, R3.w };

    v4f ld2 = { 0.0f, 0.0f, 0.0f, 0.0f };   // logdet partials per row

    #pragma unroll 1
    for (int l = 0; l < NL; ++l) {
        if (l > 0) {
            // bent identity + bounded-ratio logdet, vectorized over rows:
            //   inv = rsqrt(z^2+1); sq = (z^2+1)*inv; rat = z*(0.5*inv)+1
            //   z' = 0.5*sq + (z-0.5); rat in (0.5,1.5) -> prod of 4 safe
            v4f rat0, rat1, rat2, rat3;
            {
                v4f q = F0 * F0 + 1.0f;
                v4f inv; inv.x = rsqrtf(q.x); inv.y = rsqrtf(q.y);
                         inv.z = rsqrtf(q.z); inv.w = rsqrtf(q.w);
                v4f sq = q * inv;
                rat0 = F0 * (0.5f * inv) + 1.0f;
                F0 = 0.5f * sq + (F0 - 0.5f);
            }
            {
                v4f q = F1 * F1 + 1.0f;
                v4f inv; inv.x = rsqrtf(q.x); inv.y = rsqrtf(q.y);
                         inv.z = rsqrtf(q.z); inv.w = rsqrtf(q.w);
                v4f sq = q * inv;
                rat1 = F1 * (0.5f * inv) + 1.0f;
                F1 = 0.5f * sq + (F1 - 0.5f);
            }
            {
                v4f q = F2 * F2 + 1.0f;
                v4f inv; inv.x = rsqrtf(q.x); inv.y = rsqrtf(q.y);
                         inv.z = rsqrtf(q.z); inv.w = rsqrtf(q.w);
                v4f sq = q * inv;
                rat2 = F2 * (0.5f * inv) + 1.0f;
                F2 = 0.5f * sq + (F2 - 0.5f);
            }
            {
                v4f q = F3 * F3 + 1.0f;
                v4f inv; inv.x = rsqrtf(q.x); inv.y = rsqrtf(q.y);
                         inv.z = rsqrtf(q.z); inv.w = rsqrtf(q.w);
                v4f sq = q * inv;
                rat3 = F3 * (0.5f * inv) + 1.0f;
                F3 = 0.5f * sq + (F3 - 0.5f);
            }
            const v4f pp = (rat0 * rat1) * (rat2 * rat3);
            ld2.x += __log2f(pp.x);
            ld2.y += __log2f(pp.y);
            ld2.z += __log2f(pp.z);
            ld2.w += __log2f(pp.w);
        }

        // layer params (L2-resident)
        const float* ep = E + ((size_t)l * NB + t) * 16;
        const v4f e0 = *(const v4f*)(ep + 0);    // E[k=0][j]
        const v4f e1 = *(const v4f*)(ep + 4);
        const v4f e2 = *(const v4f*)(ep + 8);
        const v4f e3 = *(const v4f*)(ep + 12);
        const v4f bv = *(const v4f*)(bs + (size_t)l * IN_F + 4 * t);
        const int4 id = *(const int4*)(idxs + (size_t)l * IN_F + 4 * t);

        // matvec: output feature j (v4 over rows) = sum_k F_k * E[k][j] + b[j]
        v4f* stage = (l & 1) ? bufB : bufA;
        {
            v4f y0 = F0 * e0.x + F1 * e1.x + F2 * e2.x + F3 * e3.x + bv.x;
            v4f y1 = F0 * e0.y + F1 * e1.y + F2 * e2.y + F3 * e3.y + bv.y;
            v4f y2 = F0 * e0.z + F1 * e1.z + F2 * e2.z + F3 * e3.z + bv.z;
            v4f y3 = F0 * e0.w + F1 * e1.w + F2 * e2.w + F3 * e3.w + bv.w;
            stage[swz(4 * t + 0)] = y0;
            stage[swz(4 * t + 1)] = y1;
            stage[swz(4 * t + 2)] = y2;
            stage[swz(4 * t + 3)] = y3;
        }
        __syncthreads();   // the ONLY barrier per layer (double-buffered)

        // permutation gather: one aligned b128 per output feature
        F0 = stage[swz(id.x)];
        F1 = stage[swz(id.y)];
        F2 = stage[swz(id.z)];
        F3 = stage[swz(id.w)];
    }

    // outputs: transpose back to row-major, coalesced b128 stores
    float* out_z = out;
    float* out_ld = out + (size_t)BATCH_N * IN_F;
    {
        v4f w0 = { F0.x, F1.x, F2.x, F3.x };
        v4f w1 = { F0.y, F1.y, F2.y, F3.y };
        v4f w2 = { F0.z, F1.z, F2.z, F3.z };
        v4f w3 = { F0.w, F1.w, F2.w, F3.w };
        *(v4f*)(out_z + (size_t)(row0 + 0) * IN_F + 4 * t) = w0;
        *(v4f*)(out_z + (size_t)(row0 + 1) * IN_F + 4 * t) = w1;
        *(v4f*)(out_z + (size_t)(row0 + 2) * IN_F + 4 * t) = w2;
        *(v4f*)(out_z + (size_t)(row0 + 3) * IN_F + 4 * t) = w3;
    }

    // trace total (68 partials, L2-resident)
    float trs = 0.0f;
    const v4f* tp = (const v4f*)tr_part;
    #pragma unroll
    for (int i = 0; i < NL; ++i) {
        const v4f tv = tp[i];
        trs += (tv.x + tv.y) + (tv.z + tv.w);
    }

    // per-row logdet: wave shfl reduce per row component, then cross-wave
    const int wid = t >> 6;
    {
        float p = ld2.x;
        #pragma unroll
        for (int off = 32; off > 0; off >>= 1) p += __shfl_down(p, off);
        if ((t & 63) == 0) red[0][wid] = p;
    }
    {
        float p = ld2.y;
        #pragma unroll
        for (int off = 32; off > 0; off >>= 1) p += __shfl_down(p, off);
        if ((t & 63) == 0) red[1][wid] = p;
    }
    {
        float p = ld2.z;
        #pragma unroll
        for (int off = 32; off > 0; off >>= 1) p += __shfl_down(p, off);
        if ((t & 63) == 0) red[2][wid] = p;
    }
    {
        float p = ld2.w;
        #pragma unroll
        for (int off = 32; off > 0; off >>= 1) p += __shfl_down(p, off);
        if ((t & 63) == 0) red[3][wid] = p;
    }
    __syncthreads();
    if (t < RPB) {
        const float ssum = red[t][0] + red[t][1] + red[t][2] + red[t][3];
        out_ld[row0 + t] = -trs - 0.6931471805599453f * ssum;
    }
}

// ---------------------------------------------------------------------------
extern "C" void kernel_launch(void* const* d_in, const int* in_sizes, int n_in,
                              void* d_out, int out_size, void* d_ws, size_t ws_size,
                              hipStream_t stream) {
    const float* data = (const float*)d_in[0];
    const float* vs   = (const float*)d_in[1];
    const float* bs   = (const float*)d_in[2];
    const int*   idxs = (const int*)d_in[3];

    float* ws      = (float*)d_ws;
    float* tr_part = ws;          // NTRP floats (all slots written by expm)
    float* E       = ws + 128;    // 17*256*16 floats = 272 KB

    expm_kernel<<<NL, 256, 0, stream>>>(vs, E, tr_part);
    flow_kernel<<<BATCH_N / RPB, 256, 0, stream>>>(data, E, bs, idxs, tr_part, (float*)d_out);
}